// Round 2
// baseline (1905.565 us; speedup 1.0000x reference)
//
#include <hip/hip_runtime.h>
#include <hip/hip_bf16.h>

typedef short short8 __attribute__((ext_vector_type(8)));
typedef float floatx4 __attribute__((ext_vector_type(4)));

#define DEVFN static __device__ __forceinline__

// ---- static config (matches reference) ----
// Z=8,H=96,W=192; window 2x6x12 (N=144); NZ=4,NH=16,NW=16 (1024 windows)
// DIM=192, HEADS=6, HD=32, WT=64, shift=(1,3,6)
constexpr int L_TOK = 147456;          // 8*96*192
constexpr float ATT_SCALE = 0.17677669529663687f;  // 32^-0.5

// window-ordered token t -> spatial flat index (with un-roll shift add)
DEVFN int win_to_spatial(int t, int sz, int sh, int sw) {
  int w_ = t / 144;
  int n  = t - w_ * 144;
  int nz = w_ >> 8, nh = (w_ >> 4) & 15, nw = w_ & 15;
  int iz = n / 72; int rem = n - iz * 72;
  int ih = rem / 12; int iw = rem - ih * 12;
  int z = nz * 2 + iz + sz;  if (z >= 8)   z -= 8;
  int h = nh * 6 + ih + sh;  if (h >= 96)  h -= 96;
  int wc = nw * 12 + iw + sw; if (wc >= 192) wc -= 192;
  return (z * 96 + h) * 192 + wc;
}

// ---------------- LayerNorm (+optional roll+partition gather) ----------------
// 256 thr = 4 waves, one token per wave (192 channels = 3/lane)
__global__ __launch_bounds__(256) void ln_kernel(
    const float* __restrict__ x, const float* __restrict__ w,
    const float* __restrict__ b, __hip_bfloat16* __restrict__ out,
    int sz, int sh, int sw, int permute)
{
  int wv = threadIdx.x >> 6, lane = threadIdx.x & 63;
  int t = blockIdx.x * 4 + wv;
  int src = permute ? win_to_spatial(t, sz, sh, sw) : t;
  const float* xp = x + (long)src * 192;
  float v0 = xp[lane], v1 = xp[lane + 64], v2 = xp[lane + 128];
  float s = v0 + v1 + v2;
  float sq = v0 * v0 + v1 * v1 + v2 * v2;
  for (int m = 1; m < 64; m <<= 1) { s += __shfl_xor(s, m); sq += __shfl_xor(sq, m); }
  float mean = s * (1.0f / 192.0f);
  float var = sq * (1.0f / 192.0f) - mean * mean;
  float rstd = rsqrtf(var + 1e-5f);
  __hip_bfloat16* op = out + (long)t * 192;
  op[lane]       = __float2bfloat16((v0 - mean) * rstd * w[lane]       + b[lane]);
  op[lane + 64]  = __float2bfloat16((v1 - mean) * rstd * w[lane + 64]  + b[lane + 64]);
  op[lane + 128] = __float2bfloat16((v2 - mean) * rstd * w[lane + 128] + b[lane + 128]);
}

// ---------------- weight convert + transpose to bf16 (N x K row-major) -------
__global__ void convT_kernel(const float* __restrict__ in,
                             __hip_bfloat16* __restrict__ out, int K, int N)
{
  int idx = blockIdx.x * 256 + threadIdx.x;
  if (idx >= K * N) return;
  int n = idx / K, k = idx - n * K;
  out[idx] = __float2bfloat16(in[(long)k * N + n]);
}

// ---------------- relative-position bias expansion ---------------------------
// out[((wt*6+head)*144 + n)*144 + m] = tab[POS_IDX(n,m)*384 + wt*6+head]
__global__ __launch_bounds__(384) void biaspre_kernel(
    const float* __restrict__ tab, float* __restrict__ out)
{
  int bid = blockIdx.x;              // n*144+m
  int n = bid / 144, m = bid - n * 144;
  int iz1 = n / 72; int r1 = n - iz1 * 72; int ih1 = r1 / 12; int iw1 = r1 - ih1 * 12;
  int iz2 = m / 72; int r2 = m - iz2 * 72; int ih2 = r2 / 12; int iw2 = r2 - ih2 * 12;
  int idx = (iz1 + 2 * iz2) * 828 + (ih1 + 6 * ih2) * 23 + (iw1 - iw2 + 11);
  int t = threadIdx.x;               // wt*6+head
  out[((long)t * 144 + n) * 144 + m] = tab[(long)idx * 384 + t];
}

// ---------------- GEMM: C = A(MxK, bf16 rowmajor) * BT(NxK, bf16)^T ----------
// 128x64 tile, 4 waves (2x2), wave tile 64x32, MFMA 16x16x32 bf16
// MODE 0: qkv split (+bias, q*SCALE) -> oq/okk/ov bf16 [M x 192] each
// MODE 1: proj: + bias + reverse-partition scatter residual into x (f32)
// MODE 2: mlp1: + bias + gelu(erf) -> oq bf16 stride ldo
// MODE 3: mlp2: + bias + residual; LAST? d_out f32 : x f32
template<int MODE, int LAST>
__global__ __launch_bounds__(256) void gemm_kernel(
    const __hip_bfloat16* __restrict__ A, const __hip_bfloat16* __restrict__ BT,
    const float* __restrict__ cbias, int K,
    __hip_bfloat16* __restrict__ oq, __hip_bfloat16* __restrict__ okk,
    __hip_bfloat16* __restrict__ ov, float* __restrict__ x,
    float* __restrict__ outf, int sz, int sh, int sw, int ldo)
{
  __shared__ __hip_bfloat16 a_lds[128 * 40];
  __shared__ __hip_bfloat16 b_lds[64 * 40];
  int tid = threadIdx.x;
  int lane = tid & 63, wv = tid >> 6;
  int wm = wv >> 1, wn = wv & 1;
  long rowBase = (long)blockIdx.x * 128;
  int colBase = blockIdx.y * 64;
  floatx4 acc[4][2];
#pragma unroll
  for (int i = 0; i < 4; i++)
#pragma unroll
    for (int j = 0; j < 2; j++) acc[i][j] = {0.f, 0.f, 0.f, 0.f};

  int arow = tid >> 2, aseg = tid & 3;
  int koff = (lane >> 4) * 8, lc = lane & 15, lr4 = (lane >> 4) * 4;

  for (int kt = 0; kt < K; kt += 32) {
    uint4 va0 = *(const uint4*)(A + (rowBase + arow) * K + kt + aseg * 8);
    uint4 va1 = *(const uint4*)(A + (rowBase + arow + 64) * K + kt + aseg * 8);
    uint4 vb  = *(const uint4*)(BT + (long)(colBase + arow) * K + kt + aseg * 8);
    __syncthreads();
    *(uint4*)(&a_lds[arow * 40 + aseg * 8]) = va0;
    *(uint4*)(&a_lds[(arow + 64) * 40 + aseg * 8]) = va1;
    *(uint4*)(&b_lds[arow * 40 + aseg * 8]) = vb;
    __syncthreads();
    short8 bfr[2];
#pragma unroll
    for (int fn = 0; fn < 2; fn++)
      bfr[fn] = *(short8*)(&b_lds[(wn * 32 + fn * 16 + lc) * 40 + koff]);
#pragma unroll
    for (int fm = 0; fm < 4; fm++) {
      short8 afr = *(short8*)(&a_lds[(wm * 64 + fm * 16 + lc) * 40 + koff]);
#pragma unroll
      for (int fn = 0; fn < 2; fn++)
        acc[fm][fn] = __builtin_amdgcn_mfma_f32_16x16x32_bf16(afr, bfr[fn], acc[fm][fn], 0, 0, 0);
    }
  }

#pragma unroll
  for (int fm = 0; fm < 4; fm++)
#pragma unroll
    for (int fn = 0; fn < 2; fn++) {
      int col = colBase + wn * 32 + fn * 16 + lc;
      float cb = cbias[col];
#pragma unroll
      for (int r = 0; r < 4; r++) {
        long row = rowBase + wm * 64 + fm * 16 + lr4 + r;
        float val = acc[fm][fn][r] + cb;
        if constexpr (MODE == 0) {
          int sec = col / 192, c0 = col - sec * 192;
          __hip_bfloat16* dst = (sec == 0) ? oq : ((sec == 1) ? okk : ov);
          dst[row * 192 + c0] = __float2bfloat16(sec == 0 ? val * ATT_SCALE : val);
        } else if constexpr (MODE == 1) {
          int dsti = win_to_spatial((int)row, sz, sh, sw);
          long di = (long)dsti * 192 + col;
          x[di] = x[di] + val;
        } else if constexpr (MODE == 2) {
          float g = 0.5f * val * (1.0f + erff(val * 0.70710678118654752f));
          oq[row * (long)ldo + col] = __float2bfloat16(g);
        } else {
          long di = row * 192 + col;
          float nv = x[di] + val;
          if constexpr (LAST) outf[di] = nv;      // f32 final output
          else x[di] = nv;
        }
      }
    }
}

// ---------------- attention per (window, head) -------------------------------
// 192 thr = 3 waves; wave handles 3 row-tiles of 16 q-rows (144 = 3*48)
__global__ __launch_bounds__(192) void attn_kernel(
    const __hip_bfloat16* __restrict__ q, const __hip_bfloat16* __restrict__ k,
    const __hip_bfloat16* __restrict__ v, const float* __restrict__ bias_full,
    __hip_bfloat16* __restrict__ o, int masked)
{
  __shared__ __hip_bfloat16 vT[32 * 168];       // vT[d][kk], kk padded to 160(+8)
  __shared__ __hip_bfloat16 p_lds[3][16 * 168]; // per-wave P row-tile
  __shared__ int labels[144];
  int w_ = blockIdx.x, head = blockIdx.y;
  int wt = w_ >> 4;
  int tid = threadIdx.x, wv = tid / 64, lane = tid & 63;
  int lr = lane >> 4, lc = lane & 15;
  long base = ((long)w_ * 144) * 192 + head * 32;
  const __hip_bfloat16 zb = __float2bfloat16(0.0f);

  // stage v transposed into LDS
  for (int id = tid; id < 576; id += 192) {
    int tk = id >> 2, c = id & 3;
    uint4 raw = *(const uint4*)(v + base + (long)tk * 192 + c * 8);
    __hip_bfloat16 tmp[8]; *(uint4*)tmp = raw;
#pragma unroll
    for (int j = 0; j < 8; j++) vT[(c * 8 + j) * 168 + tk] = tmp[j];
  }
  for (int id = tid; id < 32 * 16; id += 192)        // zero pad kk=144..159
    vT[(id >> 4) * 168 + 144 + (id & 15)] = zb;
  for (int id = tid; id < 3 * 16 * 16; id += 192)    // zero P pad cols
    p_lds[id >> 8][((id >> 4) & 15) * 168 + 144 + (id & 15)] = zb;
  if (masked && tid < 144) {
    int nz = w_ >> 8, nh = (w_ >> 4) & 15, nw = w_ & 15;
    int iz = tid / 72; int rem = tid - iz * 72;
    int ih = rem / 12; int iw = rem - ih * 12;
    int z = nz * 2 + iz, h = nh * 6 + ih, wc = nw * 12 + iw;
    int lz = (z < 6) ? 0 : ((z < 7) ? 1 : 2);
    int lh = (h < 90) ? 0 : ((h < 93) ? 1 : 2);
    int lw = (wc < 180) ? 0 : ((wc < 186) ? 1 : 2);
    labels[tid] = lz * 9 + lh * 3 + lw;
  }
  __syncthreads();

  // K fragments (reused across row tiles): col-tile c covers tokens c*16..+15
  short8 kf[9];
#pragma unroll
  for (int c = 0; c < 9; c++)
    kf[c] = *(const short8*)(k + base + (long)(c * 16 + lc) * 192 + lr * 8);

  const float* bp = bias_full + ((long)(wt * 6 + head) * 144) * 144;
  __hip_bfloat16* pw = &p_lds[wv][0];
  const floatx4 z4 = {0.f, 0.f, 0.f, 0.f};

  for (int rti = 0; rti < 3; rti++) {
    int rt = wv * 3 + rti;
    short8 qf = *(const short8*)(q + base + (long)(rt * 16 + lc) * 192 + lr * 8);
    floatx4 s[9];
#pragma unroll
    for (int c = 0; c < 9; c++)
      s[c] = __builtin_amdgcn_mfma_f32_16x16x32_bf16(qf, kf[c], z4, 0, 0, 0);
    // bias + mask + row max
    float rmax[4] = {-1e30f, -1e30f, -1e30f, -1e30f};
#pragma unroll
    for (int c = 0; c < 9; c++) {
      int m = c * 16 + lc;
#pragma unroll
      for (int r = 0; r < 4; r++) {
        int n = rt * 16 + lr * 4 + r;
        float val = s[c][r] + bp[(long)n * 144 + m];
        if (masked && labels[n] != labels[m]) val -= 100.0f;
        s[c][r] = val;
        rmax[r] = fmaxf(rmax[r], val);
      }
    }
#pragma unroll
    for (int r = 0; r < 4; r++)
      for (int mm = 1; mm < 16; mm <<= 1) rmax[r] = fmaxf(rmax[r], __shfl_xor(rmax[r], mm));
    float rsum[4] = {0.f, 0.f, 0.f, 0.f};
#pragma unroll
    for (int c = 0; c < 9; c++)
#pragma unroll
      for (int r = 0; r < 4; r++) {
        float p = __expf(s[c][r] - rmax[r]);
        s[c][r] = p; rsum[r] += p;
      }
#pragma unroll
    for (int r = 0; r < 4; r++)
      for (int mm = 1; mm < 16; mm <<= 1) rsum[r] += __shfl_xor(rsum[r], mm);
    // stage P (bf16) to wave-private LDS
#pragma unroll
    for (int c = 0; c < 9; c++)
#pragma unroll
      for (int r = 0; r < 4; r++)
        pw[(lr * 4 + r) * 168 + c * 16 + lc] = __float2bfloat16(s[c][r]);
    __syncthreads();  // uniform (3 iters for every wave)
    // PV: o(16x32) = P(16x160) @ V(160x32), zero-padded K
    floatx4 oacc[2] = {z4, z4};
#pragma unroll
    for (int kc = 0; kc < 5; kc++) {
      short8 pa = *(short8*)(&pw[lc * 168 + kc * 32 + lr * 8]);
#pragma unroll
      for (int vt = 0; vt < 2; vt++) {
        short8 vbf = *(short8*)(&vT[(vt * 16 + lc) * 168 + kc * 32 + lr * 8]);
        oacc[vt] = __builtin_amdgcn_mfma_f32_16x16x32_bf16(pa, vbf, oacc[vt], 0, 0, 0);
      }
    }
    float inv[4];
#pragma unroll
    for (int r = 0; r < 4; r++) inv[r] = 1.0f / rsum[r];
#pragma unroll
    for (int vt = 0; vt < 2; vt++)
#pragma unroll
      for (int r = 0; r < 4; r++)
        o[base + (long)(rt * 16 + lr * 4 + r) * 192 + vt * 16 + lc] =
            __float2bfloat16(oacc[vt][r] * inv[r]);
    __syncthreads();
  }
}

// ---------------- host orchestration ----------------------------------------
extern "C" void kernel_launch(void* const* d_in, const int* in_sizes, int n_in,
                              void* d_out, int out_size, void* d_ws, size_t ws_size,
                              hipStream_t stream)
{
  const float* x_in  = (const float*)d_in[0];
  const float* n1w   = (const float*)d_in[1];
  const float* n1b   = (const float*)d_in[2];
  const float* qkvw  = (const float*)d_in[3];
  const float* qkvb  = (const float*)d_in[4];
  const float* btab  = (const float*)d_in[5];
  const float* projw = (const float*)d_in[6];
  const float* projb = (const float*)d_in[7];
  const float* n2w   = (const float*)d_in[8];
  const float* n2b   = (const float*)d_in[9];
  const float* w1    = (const float*)d_in[10];
  const float* b1    = (const float*)d_in[11];
  const float* w2    = (const float*)d_in[12];
  const float* b2    = (const float*)d_in[13];

  char* ws = (char*)d_ws;
  float* x            = (float*)(ws);                          // 113,246,208 B
  __hip_bfloat16* xw  = (__hip_bfloat16*)(ws + 113246208);     //  56,623,104 B
  __hip_bfloat16* qb  = (__hip_bfloat16*)(ws + 169869312);     // q,k,v,o = 226,492,416 B
  __hip_bfloat16* kb  = qb + 28311552;
  __hip_bfloat16* vb  = kb + 28311552;
  __hip_bfloat16* ob  = vb + 28311552;
  __hip_bfloat16* tb  = qb;                                    // MLP intermediate reuses q/k/v/o
  float* biasf        = (float*)(ws + 396361728);              //  31,850,496 B
  __hip_bfloat16* wqkvT  = (__hip_bfloat16*)(ws + 428212224);
  __hip_bfloat16* wprojT = wqkvT + 110592;
  __hip_bfloat16* w1T    = wprojT + 36864;
  __hip_bfloat16* w2T    = w1T + 147456;

  hipMemcpyAsync(x, x_in, (size_t)L_TOK * 192 * 4, hipMemcpyDeviceToDevice, stream);

  for (int layer = 0; layer < 2; layer++) {
    int sz = layer ? 1 : 0, sh = layer ? 3 : 0, sw = layer ? 6 : 0;
    int masked = layer;

    convT_kernel<<<(110592 + 255) / 256, 256, 0, stream>>>(qkvw + (long)layer * 110592, wqkvT, 192, 576);
    convT_kernel<<<(36864 + 255) / 256, 256, 0, stream>>>(projw + (long)layer * 36864, wprojT, 192, 192);
    convT_kernel<<<(147456 + 255) / 256, 256, 0, stream>>>(w1 + (long)layer * 147456, w1T, 192, 768);
    convT_kernel<<<(147456 + 255) / 256, 256, 0, stream>>>(w2 + (long)layer * 147456, w2T, 768, 192);
    biaspre_kernel<<<20736, 384, 0, stream>>>(btab + (long)layer * 3312 * 384, biasf);

    ln_kernel<<<36864, 256, 0, stream>>>(x, n1w + layer * 192, n1b + layer * 192, xw, sz, sh, sw, 1);
    gemm_kernel<0, 0><<<dim3(1152, 9), 256, 0, stream>>>(
        xw, wqkvT, qkvb + layer * 576, 192, qb, kb, vb, nullptr, nullptr, 0, 0, 0, 0);
    attn_kernel<<<dim3(1024, 6), 192, 0, stream>>>(qb, kb, vb, biasf, ob, masked);
    gemm_kernel<1, 0><<<dim3(1152, 3), 256, 0, stream>>>(
        ob, wprojT, projb + layer * 192, 192, nullptr, nullptr, nullptr, x, nullptr, sz, sh, sw, 0);
    ln_kernel<<<36864, 256, 0, stream>>>(x, n2w + layer * 192, n2b + layer * 192, xw, 0, 0, 0, 0);
    gemm_kernel<2, 0><<<dim3(1152, 12), 256, 0, stream>>>(
        xw, w1T, b1 + layer * 768, 192, tb, nullptr, nullptr, nullptr, nullptr, 0, 0, 0, 768);
    if (layer == 0)
      gemm_kernel<3, 0><<<dim3(1152, 3), 256, 0, stream>>>(
          tb, w2T, b2 + layer * 192, 768, nullptr, nullptr, nullptr, x, nullptr, 0, 0, 0, 192);
    else
      gemm_kernel<3, 1><<<dim3(1152, 3), 256, 0, stream>>>(
          tb, w2T, b2 + layer * 192, 768, nullptr, nullptr, nullptr, x,
          (float*)d_out, 0, 0, 0, 192);
  }
}

// Round 3
// 1826.515 us; speedup vs baseline: 1.0433x; 1.0433x over previous
//
#include <hip/hip_runtime.h>
#include <hip/hip_bf16.h>

typedef short short8 __attribute__((ext_vector_type(8)));
typedef float floatx4 __attribute__((ext_vector_type(4)));

#define DEVFN static __device__ __forceinline__

// ---- static config (matches reference) ----
// Z=8,H=96,W=192; window 2x6x12 (N=144); NZ=4,NH=16,NW=16 (1024 windows)
// DIM=192, HEADS=6, HD=32, WT=64, shift=(1,3,6)
constexpr int L_TOK = 147456;          // 8*96*192
constexpr float ATT_SCALE = 0.17677669529663687f;  // 32^-0.5

// window-ordered token t -> spatial flat index (with un-roll shift add)
DEVFN int win_to_spatial(int t, int sz, int sh, int sw) {
  int w_ = t / 144;
  int n  = t - w_ * 144;
  int nz = w_ >> 8, nh = (w_ >> 4) & 15, nw = w_ & 15;
  int iz = n / 72; int rem = n - iz * 72;
  int ih = rem / 12; int iw = rem - ih * 12;
  int z = nz * 2 + iz + sz;  if (z >= 8)   z -= 8;
  int h = nh * 6 + ih + sh;  if (h >= 96)  h -= 96;
  int wc = nw * 12 + iw + sw; if (wc >= 192) wc -= 192;
  return (z * 96 + h) * 192 + wc;
}

// ---------------- LayerNorm (+optional roll+partition gather) ----------------
__global__ __launch_bounds__(256) void ln_kernel(
    const float* __restrict__ x, const float* __restrict__ w,
    const float* __restrict__ b, __hip_bfloat16* __restrict__ out,
    int sz, int sh, int sw, int permute)
{
  int wv = threadIdx.x >> 6, lane = threadIdx.x & 63;
  int t = blockIdx.x * 4 + wv;
  int src = permute ? win_to_spatial(t, sz, sh, sw) : t;
  const float* xp = x + (long)src * 192;
  float v0 = xp[lane], v1 = xp[lane + 64], v2 = xp[lane + 128];
  float s = v0 + v1 + v2;
  float sq = v0 * v0 + v1 * v1 + v2 * v2;
  for (int m = 1; m < 64; m <<= 1) { s += __shfl_xor(s, m); sq += __shfl_xor(sq, m); }
  float mean = s * (1.0f / 192.0f);
  float var = sq * (1.0f / 192.0f) - mean * mean;
  float rstd = rsqrtf(var + 1e-5f);
  __hip_bfloat16* op = out + (long)t * 192;
  op[lane]       = __float2bfloat16((v0 - mean) * rstd * w[lane]       + b[lane]);
  op[lane + 64]  = __float2bfloat16((v1 - mean) * rstd * w[lane + 64]  + b[lane + 64]);
  op[lane + 128] = __float2bfloat16((v2 - mean) * rstd * w[lane + 128] + b[lane + 128]);
}

// ---------------- weight convert + transpose to bf16 (N x K row-major) -------
__global__ void convT_kernel(const float* __restrict__ in,
                             __hip_bfloat16* __restrict__ out, int K, int N)
{
  int idx = blockIdx.x * 256 + threadIdx.x;
  if (idx >= K * N) return;
  int n = idx / K, k = idx - n * K;
  out[idx] = __float2bfloat16(in[(long)k * N + n]);
}

// ---------------- relative-position bias expansion (bf16, contiguous writes) -
// one (t, ychunk) per block; out[t*20736 + n*144 + m] = tab[POS_IDX(n,m)*384 + t]
__global__ __launch_bounds__(256) void biaspre_kernel(
    const float* __restrict__ tab, __hip_bfloat16* __restrict__ out)
{
  int t = blockIdx.x;                          // wt*6+head, 0..383
  int e0 = blockIdx.y * 2304;                  // 9 chunks of 2304 = 20736
  for (int e = e0 + threadIdx.x; e < e0 + 2304; e += 256) {
    int n = e / 144, m = e - n * 144;
    int iz1 = n / 72; int r1 = n - iz1 * 72; int ih1 = r1 / 12; int iw1 = r1 - ih1 * 12;
    int iz2 = m / 72; int r2 = m - iz2 * 72; int ih2 = r2 / 12; int iw2 = r2 - ih2 * 12;
    int idx = (iz1 + 2 * iz2) * 828 + (ih1 + 6 * ih2) * 23 + (iw1 - iw2 + 11);
    out[(long)t * 20736 + e] = __float2bfloat16(tab[(long)idx * 384 + t]);
  }
}

// ---------------- GEMM: C = A(MxK, bf16 rowmajor) * BT(NxK, bf16)^T ----------
// 128x64 tile, 4 waves (2x2), wave tile 64x32, MFMA 16x16x32 bf16
template<int MODE, int LAST>
__global__ __launch_bounds__(256) void gemm_kernel(
    const __hip_bfloat16* __restrict__ A, const __hip_bfloat16* __restrict__ BT,
    const float* __restrict__ cbias, int K,
    __hip_bfloat16* __restrict__ oq, __hip_bfloat16* __restrict__ okk,
    __hip_bfloat16* __restrict__ ov, float* __restrict__ x,
    float* __restrict__ outf, int sz, int sh, int sw, int ldo)
{
  __shared__ __hip_bfloat16 a_lds[128 * 40];
  __shared__ __hip_bfloat16 b_lds[64 * 40];
  int tid = threadIdx.x;
  int lane = tid & 63, wv = tid >> 6;
  int wm = wv >> 1, wn = wv & 1;
  long rowBase = (long)blockIdx.x * 128;
  int colBase = blockIdx.y * 64;
  floatx4 acc[4][2];
#pragma unroll
  for (int i = 0; i < 4; i++)
#pragma unroll
    for (int j = 0; j < 2; j++) acc[i][j] = {0.f, 0.f, 0.f, 0.f};

  int arow = tid >> 2, aseg = tid & 3;
  int koff = (lane >> 4) * 8, lc = lane & 15, lr4 = (lane >> 4) * 4;

  for (int kt = 0; kt < K; kt += 32) {
    uint4 va0 = *(const uint4*)(A + (rowBase + arow) * K + kt + aseg * 8);
    uint4 va1 = *(const uint4*)(A + (rowBase + arow + 64) * K + kt + aseg * 8);
    uint4 vb  = *(const uint4*)(BT + (long)(colBase + arow) * K + kt + aseg * 8);
    __syncthreads();
    *(uint4*)(&a_lds[arow * 40 + aseg * 8]) = va0;
    *(uint4*)(&a_lds[(arow + 64) * 40 + aseg * 8]) = va1;
    *(uint4*)(&b_lds[arow * 40 + aseg * 8]) = vb;
    __syncthreads();
    short8 bfr[2];
#pragma unroll
    for (int fn = 0; fn < 2; fn++)
      bfr[fn] = *(short8*)(&b_lds[(wn * 32 + fn * 16 + lc) * 40 + koff]);
#pragma unroll
    for (int fm = 0; fm < 4; fm++) {
      short8 afr = *(short8*)(&a_lds[(wm * 64 + fm * 16 + lc) * 40 + koff]);
#pragma unroll
      for (int fn = 0; fn < 2; fn++)
        acc[fm][fn] = __builtin_amdgcn_mfma_f32_16x16x32_bf16(afr, bfr[fn], acc[fm][fn], 0, 0, 0);
    }
  }

#pragma unroll
  for (int fm = 0; fm < 4; fm++)
#pragma unroll
    for (int fn = 0; fn < 2; fn++) {
      int col = colBase + wn * 32 + fn * 16 + lc;
      float cb = cbias[col];
#pragma unroll
      for (int r = 0; r < 4; r++) {
        long row = rowBase + wm * 64 + fm * 16 + lr4 + r;
        float val = acc[fm][fn][r] + cb;
        if constexpr (MODE == 0) {
          int sec = col / 192, c0 = col - sec * 192;
          __hip_bfloat16* dst = (sec == 0) ? oq : ((sec == 1) ? okk : ov);
          dst[row * 192 + c0] = __float2bfloat16(sec == 0 ? val * ATT_SCALE : val);
        } else if constexpr (MODE == 1) {
          int dsti = win_to_spatial((int)row, sz, sh, sw);
          long di = (long)dsti * 192 + col;
          x[di] = x[di] + val;
        } else if constexpr (MODE == 2) {
          float g = 0.5f * val * (1.0f + erff(val * 0.70710678118654752f));
          oq[row * (long)ldo + col] = __float2bfloat16(g);
        } else {
          long di = row * 192 + col;
          float nv = x[di] + val;
          if constexpr (LAST) outf[di] = nv;      // f32 final output
          else x[di] = nv;
        }
      }
    }
}

// ---------------- attention: one block per (window, head), 9 waves -----------
// wave wv owns row tile rt=wv (16 q-rows); single pass, 2 barriers.
// XCD-chunk swizzle: all 16 windows sharing a bias plane land on one XCD.
__global__ __launch_bounds__(576) void attn_kernel(
    const __hip_bfloat16* __restrict__ q, const __hip_bfloat16* __restrict__ k,
    const __hip_bfloat16* __restrict__ v, const __hip_bfloat16* __restrict__ bias_bf,
    __hip_bfloat16* __restrict__ o, int masked)
{
  __shared__ __hip_bfloat16 vT[32 * 168];       // vT[d][kk], kk padded to 160
  __shared__ __hip_bfloat16 p_lds[9][16 * 168]; // per-wave P row-tile
  __shared__ int labels[144];

  int L = blockIdx.x;                   // 0..6143
  int xcd = L & 7, idx = L >> 3;        // assume wg->XCD round-robin
  int chunk = xcd * 48 + (idx >> 4);    // 0..383 == wt*6+head
  int within = idx & 15;
  int wt = chunk / 6, head = chunk - wt * 6;
  int w_ = wt * 16 + within;

  int tid = threadIdx.x, wv = tid >> 6, lane = tid & 63;
  int lr = lane >> 4, lc = lane & 15;
  long base = ((long)w_ * 144) * 192 + head * 32;
  const __hip_bfloat16 zb = __float2bfloat16(0.0f);

  // stage v transposed into LDS (576 threads -> one segment each)
  {
    int tk = tid >> 2, c = tid & 3;
    uint4 raw = *(const uint4*)(v + base + (long)tk * 192 + c * 8);
    __hip_bfloat16 tmp[8]; *(uint4*)tmp = raw;
#pragma unroll
    for (int j = 0; j < 8; j++) vT[(c * 8 + j) * 168 + tk] = tmp[j];
  }
  if (tid < 512)                                      // zero pad kk=144..159
    vT[(tid >> 4) * 168 + 144 + (tid & 15)] = zb;
  for (int id = tid; id < 2304; id += 576)            // zero P pad cols
    p_lds[id >> 8][((id >> 4) & 15) * 168 + 144 + (id & 15)] = zb;
  if (masked && tid < 144) {
    int nz = w_ >> 8, nh = (w_ >> 4) & 15, nw = w_ & 15;
    int iz = tid / 72; int rem = tid - iz * 72;
    int ih = rem / 12; int iw = rem - ih * 12;
    int z = nz * 2 + iz, h = nh * 6 + ih, wc = nw * 12 + iw;
    int lz = (z < 6) ? 0 : ((z < 7) ? 1 : 2);
    int lh = (h < 90) ? 0 : ((h < 93) ? 1 : 2);
    int lw = (wc < 180) ? 0 : ((wc < 186) ? 1 : 2);
    labels[tid] = lz * 9 + lh * 3 + lw;
  }
  __syncthreads();

  // K fragments: col-tile c covers tokens c*16..+15
  short8 kf[9];
#pragma unroll
  for (int c = 0; c < 9; c++)
    kf[c] = *(const short8*)(k + base + (long)(c * 16 + lc) * 192 + lr * 8);

  const __hip_bfloat16* bp = bias_bf + (long)chunk * 20736;
  __hip_bfloat16* pw = &p_lds[wv][0];
  const floatx4 z4 = {0.f, 0.f, 0.f, 0.f};

  int rt = wv;                                        // one row tile per wave
  short8 qf = *(const short8*)(q + base + (long)(rt * 16 + lc) * 192 + lr * 8);
  floatx4 s[9];
#pragma unroll
  for (int c = 0; c < 9; c++)
    s[c] = __builtin_amdgcn_mfma_f32_16x16x32_bf16(qf, kf[c], z4, 0, 0, 0);

  float rmax[4] = {-1e30f, -1e30f, -1e30f, -1e30f};
#pragma unroll
  for (int c = 0; c < 9; c++) {
    int m = c * 16 + lc;
#pragma unroll
    for (int r = 0; r < 4; r++) {
      int n = rt * 16 + lr * 4 + r;
      float val = s[c][r] + __bfloat162float(bp[(long)n * 144 + m]);
      if (masked && labels[n] != labels[m]) val -= 100.0f;
      s[c][r] = val;
      rmax[r] = fmaxf(rmax[r], val);
    }
  }
#pragma unroll
  for (int r = 0; r < 4; r++)
    for (int mm = 1; mm < 16; mm <<= 1) rmax[r] = fmaxf(rmax[r], __shfl_xor(rmax[r], mm));
  float rsum[4] = {0.f, 0.f, 0.f, 0.f};
#pragma unroll
  for (int c = 0; c < 9; c++)
#pragma unroll
    for (int r = 0; r < 4; r++) {
      float p = __expf(s[c][r] - rmax[r]);
      s[c][r] = p; rsum[r] += p;
    }
#pragma unroll
  for (int r = 0; r < 4; r++)
    for (int mm = 1; mm < 16; mm <<= 1) rsum[r] += __shfl_xor(rsum[r], mm);
  // stage P (bf16) to wave-private LDS
#pragma unroll
  for (int c = 0; c < 9; c++)
#pragma unroll
    for (int r = 0; r < 4; r++)
      pw[(lr * 4 + r) * 168 + c * 16 + lc] = __float2bfloat16(s[c][r]);
  __syncthreads();

  // PV: o(16x32) = P(16x160) @ V(160x32), zero-padded K
  floatx4 oacc[2] = {z4, z4};
#pragma unroll
  for (int kc = 0; kc < 5; kc++) {
    short8 pa = *(short8*)(&pw[lc * 168 + kc * 32 + lr * 8]);
#pragma unroll
    for (int vt = 0; vt < 2; vt++) {
      short8 vbf = *(short8*)(&vT[(vt * 16 + lc) * 168 + kc * 32 + lr * 8]);
      oacc[vt] = __builtin_amdgcn_mfma_f32_16x16x32_bf16(pa, vbf, oacc[vt], 0, 0, 0);
    }
  }
  float inv[4];
#pragma unroll
  for (int r = 0; r < 4; r++) inv[r] = 1.0f / rsum[r];
#pragma unroll
  for (int vt = 0; vt < 2; vt++)
#pragma unroll
    for (int r = 0; r < 4; r++)
      o[base + (long)(rt * 16 + lr * 4 + r) * 192 + vt * 16 + lc] =
          __float2bfloat16(oacc[vt][r] * inv[r]);
}

// ---------------- host orchestration ----------------------------------------
extern "C" void kernel_launch(void* const* d_in, const int* in_sizes, int n_in,
                              void* d_out, int out_size, void* d_ws, size_t ws_size,
                              hipStream_t stream)
{
  const float* x_in  = (const float*)d_in[0];
  const float* n1w   = (const float*)d_in[1];
  const float* n1b   = (const float*)d_in[2];
  const float* qkvw  = (const float*)d_in[3];
  const float* qkvb  = (const float*)d_in[4];
  const float* btab  = (const float*)d_in[5];
  const float* projw = (const float*)d_in[6];
  const float* projb = (const float*)d_in[7];
  const float* n2w   = (const float*)d_in[8];
  const float* n2b   = (const float*)d_in[9];
  const float* w1    = (const float*)d_in[10];
  const float* b1    = (const float*)d_in[11];
  const float* w2    = (const float*)d_in[12];
  const float* b2    = (const float*)d_in[13];

  char* ws = (char*)d_ws;
  float* x            = (float*)(ws);                          // 113,246,208 B
  __hip_bfloat16* xw  = (__hip_bfloat16*)(ws + 113246208);     //  56,623,104 B
  __hip_bfloat16* qb  = (__hip_bfloat16*)(ws + 169869312);     // q,k,v,o
  __hip_bfloat16* kb  = qb + 28311552;
  __hip_bfloat16* vb  = kb + 28311552;
  __hip_bfloat16* ob  = vb + 28311552;
  __hip_bfloat16* tb  = qb;                                    // MLP intermediate reuse
  __hip_bfloat16* biasb = (__hip_bfloat16*)(ws + 396361728);   //  15,925,248 B (bf16)
  __hip_bfloat16* wqkvT  = (__hip_bfloat16*)(ws + 428212224);
  __hip_bfloat16* wprojT = wqkvT + 110592;
  __hip_bfloat16* w1T    = wprojT + 36864;
  __hip_bfloat16* w2T    = w1T + 147456;

  hipMemcpyAsync(x, x_in, (size_t)L_TOK * 192 * 4, hipMemcpyDeviceToDevice, stream);

  for (int layer = 0; layer < 2; layer++) {
    int sz = layer ? 1 : 0, sh = layer ? 3 : 0, sw = layer ? 6 : 0;
    int masked = layer;

    convT_kernel<<<(110592 + 255) / 256, 256, 0, stream>>>(qkvw + (long)layer * 110592, wqkvT, 192, 576);
    convT_kernel<<<(36864 + 255) / 256, 256, 0, stream>>>(projw + (long)layer * 36864, wprojT, 192, 192);
    convT_kernel<<<(147456 + 255) / 256, 256, 0, stream>>>(w1 + (long)layer * 147456, w1T, 192, 768);
    convT_kernel<<<(147456 + 255) / 256, 256, 0, stream>>>(w2 + (long)layer * 147456, w2T, 768, 192);
    biaspre_kernel<<<dim3(384, 9), 256, 0, stream>>>(btab + (long)layer * 3312 * 384, biasb);

    ln_kernel<<<36864, 256, 0, stream>>>(x, n1w + layer * 192, n1b + layer * 192, xw, sz, sh, sw, 1);
    gemm_kernel<0, 0><<<dim3(1152, 9), 256, 0, stream>>>(
        xw, wqkvT, qkvb + layer * 576, 192, qb, kb, vb, nullptr, nullptr, 0, 0, 0, 0);
    attn_kernel<<<6144, 576, 0, stream>>>(qb, kb, vb, biasb, ob, masked);
    gemm_kernel<1, 0><<<dim3(1152, 3), 256, 0, stream>>>(
        ob, wprojT, projb + layer * 192, 192, nullptr, nullptr, nullptr, x, nullptr, sz, sh, sw, 0);
    ln_kernel<<<36864, 256, 0, stream>>>(x, n2w + layer * 192, n2b + layer * 192, xw, 0, 0, 0, 0);
    gemm_kernel<2, 0><<<dim3(1152, 12), 256, 0, stream>>>(
        xw, w1T, b1 + layer * 768, 192, tb, nullptr, nullptr, nullptr, nullptr, 0, 0, 0, 768);
    if (layer == 0)
      gemm_kernel<3, 0><<<dim3(1152, 3), 256, 0, stream>>>(
          tb, w2T, b2 + layer * 192, 768, nullptr, nullptr, nullptr, x, nullptr, 0, 0, 0, 192);
    else
      gemm_kernel<3, 1><<<dim3(1152, 3), 256, 0, stream>>>(
          tb, w2T, b2 + layer * 192, 768, nullptr, nullptr, nullptr, x,
          (float*)d_out, 0, 0, 0, 192);
  }
}

// Round 4
// 1549.294 us; speedup vs baseline: 1.2300x; 1.1789x over previous
//
#include <hip/hip_runtime.h>
#include <hip/hip_bf16.h>

typedef short short8 __attribute__((ext_vector_type(8)));
typedef float floatx4 __attribute__((ext_vector_type(4)));

#define DEVFN static __device__ __forceinline__

// ---- static config (matches reference) ----
// Z=8,H=96,W=192; window 2x6x12 (N=144); NZ=4,NH=16,NW=16 (1024 windows)
// DIM=192, HEADS=6, HD=32, WT=64, shift=(1,3,6)
constexpr int L_TOK = 147456;          // 8*96*192
constexpr float ATT_SCALE = 0.17677669529663687f;  // 32^-0.5

// window-ordered token t -> spatial flat index (with un-roll shift add)
DEVFN int win_to_spatial(int t, int sz, int sh, int sw) {
  int w_ = t / 144;
  int n  = t - w_ * 144;
  int nz = w_ >> 8, nh = (w_ >> 4) & 15, nw = w_ & 15;
  int iz = n / 72; int rem = n - iz * 72;
  int ih = rem / 12; int iw = rem - ih * 12;
  int z = nz * 2 + iz + sz;  if (z >= 8)   z -= 8;
  int h = nh * 6 + ih + sh;  if (h >= 96)  h -= 96;
  int wc = nw * 12 + iw + sw; if (wc >= 192) wc -= 192;
  return (z * 96 + h) * 192 + wc;
}

// ---------------- LayerNorm (+optional roll+partition gather) ----------------
__global__ __launch_bounds__(256) void ln_kernel(
    const float* __restrict__ x, const float* __restrict__ w,
    const float* __restrict__ b, __hip_bfloat16* __restrict__ out,
    int sz, int sh, int sw, int permute)
{
  int wv = threadIdx.x >> 6, lane = threadIdx.x & 63;
  int t = blockIdx.x * 4 + wv;
  int src = permute ? win_to_spatial(t, sz, sh, sw) : t;
  const float* xp = x + (long)src * 192;
  float v0 = xp[lane], v1 = xp[lane + 64], v2 = xp[lane + 128];
  float s = v0 + v1 + v2;
  float sq = v0 * v0 + v1 * v1 + v2 * v2;
  for (int m = 1; m < 64; m <<= 1) { s += __shfl_xor(s, m); sq += __shfl_xor(sq, m); }
  float mean = s * (1.0f / 192.0f);
  float var = sq * (1.0f / 192.0f) - mean * mean;
  float rstd = rsqrtf(var + 1e-5f);
  __hip_bfloat16* op = out + (long)t * 192;
  op[lane]       = __float2bfloat16((v0 - mean) * rstd * w[lane]       + b[lane]);
  op[lane + 64]  = __float2bfloat16((v1 - mean) * rstd * w[lane + 64]  + b[lane + 64]);
  op[lane + 128] = __float2bfloat16((v2 - mean) * rstd * w[lane + 128] + b[lane + 128]);
}

// ---------------- weight convert + transpose to bf16 (N x K row-major) -------
__global__ void convT_kernel(const float* __restrict__ in,
                             __hip_bfloat16* __restrict__ out, int K, int N)
{
  int idx = blockIdx.x * 256 + threadIdx.x;
  if (idx >= K * N) return;
  int n = idx / K, k = idx - n * K;
  out[idx] = __float2bfloat16(in[(long)k * N + n]);
}

// ---------------- relative-position bias expansion (bf16, contiguous writes) -
__global__ __launch_bounds__(256) void biaspre_kernel(
    const float* __restrict__ tab, __hip_bfloat16* __restrict__ out)
{
  int t = blockIdx.x;                          // wt*6+head, 0..383
  int e0 = blockIdx.y * 2304;                  // 9 chunks of 2304 = 20736
  for (int e = e0 + threadIdx.x; e < e0 + 2304; e += 256) {
    int n = e / 144, m = e - n * 144;
    int iz1 = n / 72; int r1 = n - iz1 * 72; int ih1 = r1 / 12; int iw1 = r1 - ih1 * 12;
    int iz2 = m / 72; int r2 = m - iz2 * 72; int ih2 = r2 / 12; int iw2 = r2 - ih2 * 12;
    int idx = (iz1 + 2 * iz2) * 828 + (ih1 + 6 * ih2) * 23 + (iw1 - iw2 + 11);
    out[(long)t * 20736 + e] = __float2bfloat16(tab[(long)idx * 384 + t]);
  }
}

// ---------------- GEMM: C = A(MxK, bf16 rowmajor) * BT(NxK, bf16)^T ----------
// 128x64 tile, 4 waves (2x2), wave tile 64x32, MFMA 16x16x32 bf16
template<int MODE, int LAST>
__global__ __launch_bounds__(256) void gemm_kernel(
    const __hip_bfloat16* __restrict__ A, const __hip_bfloat16* __restrict__ BT,
    const float* __restrict__ cbias, int K,
    __hip_bfloat16* __restrict__ oq, __hip_bfloat16* __restrict__ okk,
    __hip_bfloat16* __restrict__ ov, float* __restrict__ x,
    float* __restrict__ outf, int sz, int sh, int sw, int ldo)
{
  __shared__ __hip_bfloat16 a_lds[128 * 40];
  __shared__ __hip_bfloat16 b_lds[64 * 40];
  int tid = threadIdx.x;
  int lane = tid & 63, wv = tid >> 6;
  int wm = wv >> 1, wn = wv & 1;
  long rowBase = (long)blockIdx.x * 128;
  int colBase = blockIdx.y * 64;
  floatx4 acc[4][2];
#pragma unroll
  for (int i = 0; i < 4; i++)
#pragma unroll
    for (int j = 0; j < 2; j++) acc[i][j] = {0.f, 0.f, 0.f, 0.f};

  int arow = tid >> 2, aseg = tid & 3;
  int koff = (lane >> 4) * 8, lc = lane & 15, lr4 = (lane >> 4) * 4;

  for (int kt = 0; kt < K; kt += 32) {
    uint4 va0 = *(const uint4*)(A + (rowBase + arow) * K + kt + aseg * 8);
    uint4 va1 = *(const uint4*)(A + (rowBase + arow + 64) * K + kt + aseg * 8);
    uint4 vb  = *(const uint4*)(BT + (long)(colBase + arow) * K + kt + aseg * 8);
    __syncthreads();
    *(uint4*)(&a_lds[arow * 40 + aseg * 8]) = va0;
    *(uint4*)(&a_lds[(arow + 64) * 40 + aseg * 8]) = va1;
    *(uint4*)(&b_lds[arow * 40 + aseg * 8]) = vb;
    __syncthreads();
    short8 bfr[2];
#pragma unroll
    for (int fn = 0; fn < 2; fn++)
      bfr[fn] = *(short8*)(&b_lds[(wn * 32 + fn * 16 + lc) * 40 + koff]);
#pragma unroll
    for (int fm = 0; fm < 4; fm++) {
      short8 afr = *(short8*)(&a_lds[(wm * 64 + fm * 16 + lc) * 40 + koff]);
#pragma unroll
      for (int fn = 0; fn < 2; fn++)
        acc[fm][fn] = __builtin_amdgcn_mfma_f32_16x16x32_bf16(afr, bfr[fn], acc[fm][fn], 0, 0, 0);
    }
  }

#pragma unroll
  for (int fm = 0; fm < 4; fm++)
#pragma unroll
    for (int fn = 0; fn < 2; fn++) {
      int col = colBase + wn * 32 + fn * 16 + lc;
      float cb = cbias[col];
#pragma unroll
      for (int r = 0; r < 4; r++) {
        long row = rowBase + wm * 64 + fm * 16 + lr4 + r;
        float val = acc[fm][fn][r] + cb;
        if constexpr (MODE == 0) {
          int sec = col / 192, c0 = col - sec * 192;
          __hip_bfloat16* dst = (sec == 0) ? oq : ((sec == 1) ? okk : ov);
          dst[row * 192 + c0] = __float2bfloat16(sec == 0 ? val * ATT_SCALE : val);
        } else if constexpr (MODE == 1) {
          int dsti = win_to_spatial((int)row, sz, sh, sw);
          long di = (long)dsti * 192 + col;
          x[di] = x[di] + val;
        } else if constexpr (MODE == 2) {
          float g = 0.5f * val * (1.0f + erff(val * 0.70710678118654752f));
          oq[row * (long)ldo + col] = __float2bfloat16(g);
        } else {
          long di = row * 192 + col;
          float nv = x[di] + val;
          if constexpr (LAST) outf[di] = nv;      // f32 final output
          else x[di] = nv;
        }
      }
    }
}

// ---------------- attention: block per (wt, head, half), 8-window loop -------
// 9 waves; wave wv owns q-row tile rt=wv (16 rows). Bias plane cached in LDS.
// V double-buffered in LDS, loads issued before QK^T (async-STAGE split).
__global__ __launch_bounds__(576) void attn_kernel(
    const __hip_bfloat16* __restrict__ q, const __hip_bfloat16* __restrict__ k,
    const __hip_bfloat16* __restrict__ v, const __hip_bfloat16* __restrict__ bias_bf,
    __hip_bfloat16* __restrict__ o, int masked)
{
  __shared__ __hip_bfloat16 biasS[144 * 152];   // 43,776 B, stride 152 (b128-aligned)
  __shared__ __hip_bfloat16 vT[2][32 * 168];    // 21,504 B double-buffered V^T
  __shared__ __hip_bfloat16 pS[9][16 * 168];    // 48,384 B wave-private P

  int bid = blockIdx.x;                 // 0..767; bid and bid+384 share bias plane
  int chunk = bid & 383, half = bid >> 9 ? 0 : bid >> 8 >> 1;  // placeholder, fixed below
  chunk = bid % 384; half = bid / 384;
  int wt = chunk / 6, head = chunk - wt * 6;

  int tid = threadIdx.x, wv = tid >> 6, lane = tid & 63;
  int lr = lane >> 4, lc = lane & 15;
  const __hip_bfloat16 zb = __float2bfloat16(0.0f);

  // ---- prologue staging ----
  // bias plane (contiguous 20736 bf16) -> LDS rows stride 152
  {
    const __hip_bfloat16* bp = bias_bf + (long)chunk * 20736;
    for (int id = tid; id < 2592; id += 576) {
      int row = id / 18, cc = id - row * 18;
      uint4 raw = *(const uint4*)(bp + row * 144 + cc * 8);
      *(uint4*)(&biasS[row * 152 + cc * 8]) = raw;
    }
  }
  int w0 = wt * 16 + half * 8;
  {
    long base0 = ((long)w0 * 144) * 192 + head * 32;
    int tk = tid >> 2, c = tid & 3;
    uint4 raw = *(const uint4*)(v + base0 + (long)tk * 192 + c * 8);
    __hip_bfloat16 tmp[8]; *(uint4*)tmp = raw;
#pragma unroll
    for (int j = 0; j < 8; j++) vT[0][(c * 8 + j) * 168 + tk] = tmp[j];
  }
  for (int id = tid; id < 1024; id += 576)            // zero pad vT cols 144..159 (both bufs)
    vT[id >> 9][((id >> 4) & 31) * 168 + 144 + (id & 15)] = zb;
  for (int id = tid; id < 2304; id += 576)            // zero pad P cols 144..159
    pS[id >> 8][((id >> 4) & 15) * 168 + 144 + (id & 15)] = zb;

  // position signatures (window-independent): bit0=iz, bit1=ih>=3, bit2=iw>=6
  int rt = wv;
  int sign_[4], sigm_[9];
#pragma unroll
  for (int r = 0; r < 4; r++) {
    int p = rt * 16 + lr * 4 + r;
    int iz = p / 72; int rem = p - iz * 72; int ih = rem / 12; int iw = rem - ih * 12;
    sign_[r] = iz | ((ih >= 3) << 1) | ((iw >= 6) << 2);
  }
#pragma unroll
  for (int c = 0; c < 9; c++) {
    int p = c * 16 + lc;
    int iz = p / 72; int rem = p - iz * 72; int ih = rem / 12; int iw = rem - ih * 12;
    sigm_[c] = iz | ((ih >= 3) << 1) | ((iw >= 6) << 2);
  }
  __syncthreads();

  __hip_bfloat16* pw = &pS[wv][0];
  const floatx4 z4 = {0.f, 0.f, 0.f, 0.f};
  int cur = 0;

  for (int wi = 0; wi < 8; wi++) {
    int w_ = w0 + wi;
    long base = ((long)w_ * 144) * 192 + head * 32;
    // issue next window's V load early (latency hides under QK^T+softmax)
    uint4 vreg;
    if (wi < 7)
      vreg = *(const uint4*)(v + base + 144 * 192 + (long)(tid >> 2) * 192 + (tid & 3) * 8);

    // window mask gate: which sig bits can differ within this window
    int g = 0;
    if (masked) {
      int nz = w_ >> 8, nh = (w_ >> 4) & 15, nw = w_ & 15;
      g = (nz == 3 ? 1 : 0) | (nh == 15 ? 2 : 0) | (nw == 15 ? 4 : 0);
    }

    // QK^T
    short8 qf = *(const short8*)(q + base + (long)(rt * 16 + lc) * 192 + lr * 8);
    floatx4 s[9];
#pragma unroll
    for (int c = 0; c < 9; c++) {
      short8 kf = *(const short8*)(k + base + (long)(c * 16 + lc) * 192 + lr * 8);
      s[c] = __builtin_amdgcn_mfma_f32_16x16x32_bf16(qf, kf, z4, 0, 0, 0);
    }

    // bias (LDS) + mask + row max
    float rmax[4] = {-1e30f, -1e30f, -1e30f, -1e30f};
#pragma unroll
    for (int c = 0; c < 9; c++) {
      int m = c * 16 + lc;
#pragma unroll
      for (int r = 0; r < 4; r++) {
        int n = rt * 16 + lr * 4 + r;
        float val = s[c][r] + __bfloat162float(biasS[n * 152 + m]);
        if ((sign_[r] ^ sigm_[c]) & g) val -= 100.0f;
        s[c][r] = val;
        rmax[r] = fmaxf(rmax[r], val);
      }
    }
#pragma unroll
    for (int r = 0; r < 4; r++)
      for (int mm = 1; mm < 16; mm <<= 1) rmax[r] = fmaxf(rmax[r], __shfl_xor(rmax[r], mm));
    float rsum[4] = {0.f, 0.f, 0.f, 0.f};
#pragma unroll
    for (int c = 0; c < 9; c++)
#pragma unroll
      for (int r = 0; r < 4; r++) {
        float p = __expf(s[c][r] - rmax[r]);
        s[c][r] = p; rsum[r] += p;
      }
#pragma unroll
    for (int r = 0; r < 4; r++)
      for (int mm = 1; mm < 16; mm <<= 1) rsum[r] += __shfl_xor(rsum[r], mm);

    // P -> wave-private LDS (no barrier needed before PV)
#pragma unroll
    for (int c = 0; c < 9; c++)
#pragma unroll
      for (int r = 0; r < 4; r++)
        pw[(lr * 4 + r) * 168 + c * 16 + lc] = __float2bfloat16(s[c][r]);

    // PV: o(16x32) = P(16x160) @ V(160x32)
    floatx4 oacc[2] = {z4, z4};
#pragma unroll
    for (int kc = 0; kc < 5; kc++) {
      short8 pa = *(short8*)(&pw[lc * 168 + kc * 32 + lr * 8]);
#pragma unroll
      for (int vt = 0; vt < 2; vt++) {
        short8 vbf = *(short8*)(&vT[cur][(vt * 16 + lc) * 168 + kc * 32 + lr * 8]);
        oacc[vt] = __builtin_amdgcn_mfma_f32_16x16x32_bf16(pa, vbf, oacc[vt], 0, 0, 0);
      }
    }
    float inv[4];
#pragma unroll
    for (int r = 0; r < 4; r++) inv[r] = 1.0f / rsum[r];
#pragma unroll
    for (int vt = 0; vt < 2; vt++)
#pragma unroll
      for (int r = 0; r < 4; r++)
        o[base + (long)(rt * 16 + lr * 4 + r) * 192 + vt * 16 + lc] =
            __float2bfloat16(oacc[vt][r] * inv[r]);

    __syncthreads();                    // all waves done reading vT[cur]
    if (wi < 7) {
      __hip_bfloat16 tmp[8]; *(uint4*)tmp = vreg;
      int tk = tid >> 2, c = tid & 3;
#pragma unroll
      for (int j = 0; j < 8; j++) vT[cur ^ 1][(c * 8 + j) * 168 + tk] = tmp[j];
      __syncthreads();                  // vT[cur^1] ready
      cur ^= 1;
    }
  }
}

// ---------------- host orchestration ----------------------------------------
extern "C" void kernel_launch(void* const* d_in, const int* in_sizes, int n_in,
                              void* d_out, int out_size, void* d_ws, size_t ws_size,
                              hipStream_t stream)
{
  const float* x_in  = (const float*)d_in[0];
  const float* n1w   = (const float*)d_in[1];
  const float* n1b   = (const float*)d_in[2];
  const float* qkvw  = (const float*)d_in[3];
  const float* qkvb  = (const float*)d_in[4];
  const float* btab  = (const float*)d_in[5];
  const float* projw = (const float*)d_in[6];
  const float* projb = (const float*)d_in[7];
  const float* n2w   = (const float*)d_in[8];
  const float* n2b   = (const float*)d_in[9];
  const float* w1    = (const float*)d_in[10];
  const float* b1    = (const float*)d_in[11];
  const float* w2    = (const float*)d_in[12];
  const float* b2    = (const float*)d_in[13];

  char* ws = (char*)d_ws;
  float* x            = (float*)(ws);                          // 113,246,208 B
  __hip_bfloat16* xw  = (__hip_bfloat16*)(ws + 113246208);     //  56,623,104 B
  __hip_bfloat16* qb  = (__hip_bfloat16*)(ws + 169869312);     // q,k,v,o
  __hip_bfloat16* kb  = qb + 28311552;
  __hip_bfloat16* vb  = kb + 28311552;
  __hip_bfloat16* ob  = vb + 28311552;
  __hip_bfloat16* tb  = qb;                                    // MLP intermediate reuse
  __hip_bfloat16* biasb = (__hip_bfloat16*)(ws + 396361728);   //  15,925,248 B (bf16)
  __hip_bfloat16* wqkvT  = (__hip_bfloat16*)(ws + 428212224);
  __hip_bfloat16* wprojT = wqkvT + 110592;
  __hip_bfloat16* w1T    = wprojT + 36864;
  __hip_bfloat16* w2T    = w1T + 147456;

  hipMemcpyAsync(x, x_in, (size_t)L_TOK * 192 * 4, hipMemcpyDeviceToDevice, stream);

  for (int layer = 0; layer < 2; layer++) {
    int sz = layer ? 1 : 0, sh = layer ? 3 : 0, sw = layer ? 6 : 0;
    int masked = layer;

    convT_kernel<<<(110592 + 255) / 256, 256, 0, stream>>>(qkvw + (long)layer * 110592, wqkvT, 192, 576);
    convT_kernel<<<(36864 + 255) / 256, 256, 0, stream>>>(projw + (long)layer * 36864, wprojT, 192, 192);
    convT_kernel<<<(147456 + 255) / 256, 256, 0, stream>>>(w1 + (long)layer * 147456, w1T, 192, 768);
    convT_kernel<<<(147456 + 255) / 256, 256, 0, stream>>>(w2 + (long)layer * 147456, w2T, 768, 192);
    biaspre_kernel<<<dim3(384, 9), 256, 0, stream>>>(btab + (long)layer * 3312 * 384, biasb);

    ln_kernel<<<36864, 256, 0, stream>>>(x, n1w + layer * 192, n1b + layer * 192, xw, sz, sh, sw, 1);
    gemm_kernel<0, 0><<<dim3(1152, 9), 256, 0, stream>>>(
        xw, wqkvT, qkvb + layer * 576, 192, qb, kb, vb, nullptr, nullptr, 0, 0, 0, 0);
    attn_kernel<<<768, 576, 0, stream>>>(qb, kb, vb, biasb, ob, masked);
    gemm_kernel<1, 0><<<dim3(1152, 3), 256, 0, stream>>>(
        ob, wprojT, projb + layer * 192, 192, nullptr, nullptr, nullptr, x, nullptr, sz, sh, sw, 0);
    ln_kernel<<<36864, 256, 0, stream>>>(x, n2w + layer * 192, n2b + layer * 192, xw, 0, 0, 0, 0);
    gemm_kernel<2, 0><<<dim3(1152, 12), 256, 0, stream>>>(
        xw, w1T, b1 + layer * 768, 192, tb, nullptr, nullptr, nullptr, nullptr, 0, 0, 0, 768);
    if (layer == 0)
      gemm_kernel<3, 0><<<dim3(1152, 3), 256, 0, stream>>>(
          tb, w2T, b2 + layer * 192, 768, nullptr, nullptr, nullptr, x, nullptr, 0, 0, 0, 192);
    else
      gemm_kernel<3, 1><<<dim3(1152, 3), 256, 0, stream>>>(
          tb, w2T, b2 + layer * 192, 768, nullptr, nullptr, nullptr, x,
          (float*)d_out, 0, 0, 0, 192);
  }
}

// Round 5
// 1499.572 us; speedup vs baseline: 1.2707x; 1.0332x over previous
//
#include <hip/hip_runtime.h>
#include <hip/hip_bf16.h>

typedef short short8 __attribute__((ext_vector_type(8)));
typedef short s4b __attribute__((ext_vector_type(4)));
typedef float floatx4 __attribute__((ext_vector_type(4)));
typedef unsigned int u32;

#define DEVFN static __device__ __forceinline__

// ---- static config (matches reference) ----
// Z=8,H=96,W=192; window 2x6x12 (N=144); NZ=4,NH=16,NW=16 (1024 windows)
// DIM=192, HEADS=6, HD=32, WT=64, shift=(1,3,6)
constexpr int L_TOK = 147456;          // 8*96*192
constexpr float ATT_SCALE = 0.17677669529663687f;  // 32^-0.5

DEVFN int win_to_spatial(int t, int sz, int sh, int sw) {
  int w_ = t / 144;
  int n  = t - w_ * 144;
  int nz = w_ >> 8, nh = (w_ >> 4) & 15, nw = w_ & 15;
  int iz = n / 72; int rem = n - iz * 72;
  int ih = rem / 12; int iw = rem - ih * 12;
  int z = nz * 2 + iz + sz;  if (z >= 8)   z -= 8;
  int h = nh * 6 + ih + sh;  if (h >= 96)  h -= 96;
  int wc = nw * 12 + iw + sw; if (wc >= 192) wc -= 192;
  return (z * 96 + h) * 192 + wc;
}

// direct-to-LDS 16B DMA; dest = lds base + lane*16, src per-lane
DEVFN void gload16(const void* g, void* l) {
  __builtin_amdgcn_global_load_lds(
      (const __attribute__((address_space(1))) u32*)(g),
      (__attribute__((address_space(3))) u32*)(l), 16, 0, 0);
}

// ---------------- LayerNorm (+optional roll+partition gather) ----------------
__global__ __launch_bounds__(256) void ln_kernel(
    const float* __restrict__ x, const float* __restrict__ w,
    const float* __restrict__ b, __hip_bfloat16* __restrict__ out,
    int sz, int sh, int sw, int permute)
{
  int wv = threadIdx.x >> 6, lane = threadIdx.x & 63;
  int t = blockIdx.x * 4 + wv;
  int src = permute ? win_to_spatial(t, sz, sh, sw) : t;
  const float* xp = x + (long)src * 192;
  float v0 = xp[lane], v1 = xp[lane + 64], v2 = xp[lane + 128];
  float s = v0 + v1 + v2;
  float sq = v0 * v0 + v1 * v1 + v2 * v2;
  for (int m = 1; m < 64; m <<= 1) { s += __shfl_xor(s, m); sq += __shfl_xor(sq, m); }
  float mean = s * (1.0f / 192.0f);
  float var = sq * (1.0f / 192.0f) - mean * mean;
  float rstd = rsqrtf(var + 1e-5f);
  __hip_bfloat16* op = out + (long)t * 192;
  op[lane]       = __float2bfloat16((v0 - mean) * rstd * w[lane]       + b[lane]);
  op[lane + 64]  = __float2bfloat16((v1 - mean) * rstd * w[lane + 64]  + b[lane + 64]);
  op[lane + 128] = __float2bfloat16((v2 - mean) * rstd * w[lane + 128] + b[lane + 128]);
}

// ---------------- weight convert + transpose to bf16 (N x K row-major) -------
__global__ void convT_kernel(const float* __restrict__ in,
                             __hip_bfloat16* __restrict__ out, int K, int N)
{
  int idx = blockIdx.x * 256 + threadIdx.x;
  if (idx >= K * N) return;
  int n = idx / K, k = idx - n * K;
  out[idx] = __float2bfloat16(in[(long)k * N + n]);
}

// ---------------- bias expansion, TRANSPOSED: out[t][m][n] -------------------
__global__ __launch_bounds__(256) void biaspre_kernel(
    const float* __restrict__ tab, __hip_bfloat16* __restrict__ out)
{
  int t = blockIdx.x;                          // wt*6+head, 0..383
  int e0 = blockIdx.y * 2304;
  for (int e = e0 + threadIdx.x; e < e0 + 2304; e += 256) {
    int m = e / 144, n = e - m * 144;          // e = m*144 + n (key-major)
    int izn = n / 72, rn = n - izn * 72, ihn = rn / 12, iwn = rn - ihn * 12;
    int izm = m / 72, rm = m - izm * 72, ihm = rm / 12, iwm = rm - ihm * 12;
    int idx = (izn + 2 * izm) * 828 + (ihn + 6 * ihm) * 23 + (iwn - iwm + 11);
    out[(long)t * 20736 + e] = __float2bfloat16(tab[(long)idx * 384 + t]);
  }
}

// ---------------- GEMM: full-K LDS stage via global_load_lds -----------------
// 128x64 tile, 4 waves (2x2). K staged in 192-panels; swizzled source so
// LDS stays linear (rule: inverse-swz source + swz ds_read).
// MODE 0: qkv split (+bias, q*SCALE) -> HEAD-MAJOR q/k/v [head][L][32]
// MODE 1: proj (A = head-major o, remapped at staging) + residual scatter to x
// MODE 2: mlp1 + gelu -> oq bf16 stride ldo
// MODE 3: mlp2 + residual; LAST? d_out f32 : x f32
template<int MODE, int LAST>
__global__ __launch_bounds__(256) void gemm_kernel(
    const __hip_bfloat16* __restrict__ A, const __hip_bfloat16* __restrict__ BT,
    const float* __restrict__ cbias, int K,
    __hip_bfloat16* __restrict__ oq, __hip_bfloat16* __restrict__ okk,
    __hip_bfloat16* __restrict__ ov, float* __restrict__ x,
    float* __restrict__ outf, int sz, int sh, int sw, int ldo)
{
  __shared__ __hip_bfloat16 a_lds[128 * 192];   // 49152 B, linear (swz data)
  __shared__ __hip_bfloat16 b_lds[64 * 192];    // 24576 B
  int tid = threadIdx.x, lane = tid & 63, wv = tid >> 6;
  int wm = wv >> 1, wn = wv & 1;
  int lc = lane & 15, lr = lane >> 4, lr4 = lr * 4;
  long rowBase = (long)blockIdx.x * 128;
  int colBase = blockIdx.y * 64;
  floatx4 acc[4][2];
#pragma unroll
  for (int i = 0; i < 4; i++)
#pragma unroll
    for (int j = 0; j < 2; j++) acc[i][j] = {0.f, 0.f, 0.f, 0.f};

  const char* Ac = (const char*)A;
  const char* Bc = (const char*)BT;
  int npan = K / 192;

  for (int pan = 0; pan < npan; pan++) {
    if (pan) __syncthreads();                   // LDS reuse safe
    long kb = (long)pan * 384;                  // panel byte offset in a row
    // A: 48 x 1KB DMA, wave-strided
#pragma unroll
    for (int i = 0; i < 12; i++) {
      int ii = i * 4 + wv;
      int p = ii * 1024 + lane * 16;
      int row = p / 384, cb = p - row * 384;
      int sc = (cb >> 4) ^ (row & 7);           // inverse swizzle on source
      const char* g;
      if constexpr (MODE == 1) {                // A is head-major o
        int ch = sc * 8; int head = ch >> 5;
        g = Ac + (((long)head * L_TOK + rowBase + row) * 32 + (ch & 31)) * 2;
      } else {
        g = Ac + (rowBase + row) * (long)K * 2 + kb + sc * 16;
      }
      gload16(g, (char*)a_lds + ii * 1024);
    }
    // B: 24 x 1KB DMA
#pragma unroll
    for (int i = 0; i < 6; i++) {
      int ii = i * 4 + wv;
      int p = ii * 1024 + lane * 16;
      int row = p / 384, cb = p - row * 384;
      int sc = (cb >> 4) ^ (row & 7);
      const char* g = Bc + (colBase + row) * (long)K * 2 + kb + sc * 16;
      gload16(g, (char*)b_lds + ii * 1024);
    }
    __syncthreads();                            // vmcnt(0) drain + barrier
#pragma unroll
    for (int kt = 0; kt < 6; kt++) {
      short8 bfr[2];
#pragma unroll
      for (int fn = 0; fn < 2; fn++) {
        int rb = wn * 32 + fn * 16 + lc;
        bfr[fn] = *(const short8*)((const char*)b_lds + rb * 384 + ((kt * 4 + lr) ^ (rb & 7)) * 16);
      }
#pragma unroll
      for (int fm = 0; fm < 4; fm++) {
        int ra = wm * 64 + fm * 16 + lc;
        short8 afr = *(const short8*)((const char*)a_lds + ra * 384 + ((kt * 4 + lr) ^ (ra & 7)) * 16);
#pragma unroll
        for (int fn = 0; fn < 2; fn++)
          acc[fm][fn] = __builtin_amdgcn_mfma_f32_16x16x32_bf16(afr, bfr[fn], acc[fm][fn], 0, 0, 0);
      }
    }
  }

#pragma unroll
  for (int fm = 0; fm < 4; fm++)
#pragma unroll
    for (int fn = 0; fn < 2; fn++) {
      int col = colBase + wn * 32 + fn * 16 + lc;
      float cb = cbias[col];
#pragma unroll
      for (int r = 0; r < 4; r++) {
        long row = rowBase + wm * 64 + fm * 16 + lr4 + r;
        float val = acc[fm][fn][r] + cb;
        if constexpr (MODE == 0) {
          int sec = col / 192, c0 = col - sec * 192;
          int head = c0 >> 5, ch = c0 & 31;
          __hip_bfloat16* dst = (sec == 0) ? oq : ((sec == 1) ? okk : ov);
          dst[((long)head * L_TOK + row) * 32 + ch] =
              __float2bfloat16(sec == 0 ? val * ATT_SCALE : val);
        } else if constexpr (MODE == 1) {
          int dsti = win_to_spatial((int)row, sz, sh, sw);
          long di = (long)dsti * 192 + col;
          x[di] = x[di] + val;
        } else if constexpr (MODE == 2) {
          float g = 0.5f * val * (1.0f + erff(val * 0.70710678118654752f));
          oq[row * (long)ldo + col] = __float2bfloat16(g);
        } else {
          long di = row * 192 + col;
          float nv = x[di] + val;
          if constexpr (LAST) outf[di] = nv;
          else x[di] = nv;
        }
      }
    }
}

// ---------------- attention: block per (wt, head, half), 8-window loop -------
// q/k/v/o are HEAD-MAJOR [head][L][32]. Bias plane [m][n] cached in LDS,
// read as b64. V double-buffered, async-STAGE split.
__global__ __launch_bounds__(576) void attn_kernel(
    const __hip_bfloat16* __restrict__ q, const __hip_bfloat16* __restrict__ k,
    const __hip_bfloat16* __restrict__ v, const __hip_bfloat16* __restrict__ bias_bf,
    __hip_bfloat16* __restrict__ o, int masked)
{
  __shared__ __hip_bfloat16 biasS[144 * 152];   // [m][n] stride 152
  __shared__ __hip_bfloat16 vT[2][32 * 168];
  __shared__ __hip_bfloat16 pS[9][16 * 168];

  int bid = blockIdx.x;                 // 0..767; bid, bid+384 share bias plane
  int chunk = bid % 384, half = bid / 384;
  int wt = chunk / 6, head = chunk - wt * 6;

  int tid = threadIdx.x, wv = tid >> 6, lane = tid & 63;
  int lr = lane >> 4, lc = lane & 15, lr4 = lr * 4;
  const __hip_bfloat16 zb = __float2bfloat16(0.0f);

  // bias plane -> LDS (linear rows of 144 into stride-152 rows)
  {
    const __hip_bfloat16* bp = bias_bf + (long)chunk * 20736;
    for (int id = tid; id < 2592; id += 576) {
      int row = id / 18, cc = id - row * 18;
      uint4 raw = *(const uint4*)(bp + row * 144 + cc * 8);
      *(uint4*)(&biasS[row * 152 + cc * 8]) = raw;
    }
  }
  int w0 = wt * 16 + half * 8;
  long hb = (long)head * L_TOK * 32;
  {
    long base0 = hb + (long)w0 * 144 * 32;
    int tk = tid >> 2, c = tid & 3;
    uint4 raw = *(const uint4*)(v + base0 + tk * 32 + c * 8);
    __hip_bfloat16 tmp[8]; *(uint4*)tmp = raw;
#pragma unroll
    for (int j = 0; j < 8; j++) vT[0][(c * 8 + j) * 168 + tk] = tmp[j];
  }
  for (int id = tid; id < 1024; id += 576)
    vT[id >> 9][((id >> 4) & 31) * 168 + 144 + (id & 15)] = zb;
  for (int id = tid; id < 2304; id += 576)
    pS[id >> 8][((id >> 4) & 15) * 168 + 144 + (id & 15)] = zb;

  // position signatures: bit0=iz, bit1=ih>=3, bit2=iw>=6
  int rt = wv;
  int sign_[4], sigm_[9];
#pragma unroll
  for (int r = 0; r < 4; r++) {
    int p = rt * 16 + lr4 + r;
    int iz = p / 72; int rem = p - iz * 72; int ih = rem / 12; int iw = rem - ih * 12;
    sign_[r] = iz | ((ih >= 3) << 1) | ((iw >= 6) << 2);
  }
#pragma unroll
  for (int c = 0; c < 9; c++) {
    int p = c * 16 + lc;
    int iz = p / 72; int rem = p - iz * 72; int ih = rem / 12; int iw = rem - ih * 12;
    sigm_[c] = iz | ((ih >= 3) << 1) | ((iw >= 6) << 2);
  }
  __syncthreads();

  __hip_bfloat16* pw = &pS[wv][0];
  const floatx4 z4 = {0.f, 0.f, 0.f, 0.f};
  int cur = 0;

  for (int wi = 0; wi < 8; wi++) {
    int w_ = w0 + wi;
    long base = hb + (long)w_ * 144 * 32;
    uint4 vreg;
    if (wi < 7)
      vreg = *(const uint4*)(v + base + 144 * 32 + (tid >> 2) * 32 + (tid & 3) * 8);

    int g = 0;
    if (masked) {
      int nz = w_ >> 8, nh = (w_ >> 4) & 15, nw = w_ & 15;
      g = (nz == 3 ? 1 : 0) | (nh == 15 ? 2 : 0) | (nw == 15 ? 4 : 0);
    }

    short8 qf = *(const short8*)(q + base + (rt * 16 + lc) * 32 + lr * 8);
    floatx4 s[9];
#pragma unroll
    for (int c = 0; c < 9; c++) {
      short8 kf = *(const short8*)(k + base + (c * 16 + lc) * 32 + lr * 8);
      s[c] = __builtin_amdgcn_mfma_f32_16x16x32_bf16(qf, kf, z4, 0, 0, 0);
    }

    float rmax[4] = {-1e30f, -1e30f, -1e30f, -1e30f};
#pragma unroll
    for (int c = 0; c < 9; c++) {
      __hip_bfloat16 bb[4];
      *(s4b*)bb = *(const s4b*)(&biasS[(c * 16 + lc) * 152 + rt * 16 + lr4]);
#pragma unroll
      for (int r = 0; r < 4; r++) {
        float val = s[c][r] + __bfloat162float(bb[r]);
        if ((sign_[r] ^ sigm_[c]) & g) val -= 100.0f;
        s[c][r] = val;
        rmax[r] = fmaxf(rmax[r], val);
      }
    }
#pragma unroll
    for (int r = 0; r < 4; r++)
      for (int mm = 1; mm < 16; mm <<= 1) rmax[r] = fmaxf(rmax[r], __shfl_xor(rmax[r], mm));
    float rsum[4] = {0.f, 0.f, 0.f, 0.f};
#pragma unroll
    for (int c = 0; c < 9; c++)
#pragma unroll
      for (int r = 0; r < 4; r++) {
        float p = __expf(s[c][r] - rmax[r]);
        s[c][r] = p; rsum[r] += p;
      }
#pragma unroll
    for (int r = 0; r < 4; r++)
      for (int mm = 1; mm < 16; mm <<= 1) rsum[r] += __shfl_xor(rsum[r], mm);

#pragma unroll
    for (int c = 0; c < 9; c++)
#pragma unroll
      for (int r = 0; r < 4; r++)
        pw[(lr4 + r) * 168 + c * 16 + lc] = __float2bfloat16(s[c][r]);

    floatx4 oacc[2] = {z4, z4};
#pragma unroll
    for (int kc = 0; kc < 5; kc++) {
      short8 pa = *(short8*)(&pw[lc * 168 + kc * 32 + lr * 8]);
#pragma unroll
      for (int vt = 0; vt < 2; vt++) {
        short8 vbf = *(short8*)(&vT[cur][(vt * 16 + lc) * 168 + kc * 32 + lr * 8]);
        oacc[vt] = __builtin_amdgcn_mfma_f32_16x16x32_bf16(pa, vbf, oacc[vt], 0, 0, 0);
      }
    }
    float inv[4];
#pragma unroll
    for (int r = 0; r < 4; r++) inv[r] = 1.0f / rsum[r];
#pragma unroll
    for (int vt = 0; vt < 2; vt++)
#pragma unroll
      for (int r = 0; r < 4; r++)
        o[base + (rt * 16 + lr4 + r) * 32 + vt * 16 + lc] =
            __float2bfloat16(oacc[vt][r] * inv[r]);

    __syncthreads();
    if (wi < 7) {
      __hip_bfloat16 tmp[8]; *(uint4*)tmp = vreg;
      int tk = tid >> 2, c = tid & 3;
#pragma unroll
      for (int j = 0; j < 8; j++) vT[cur ^ 1][(c * 8 + j) * 168 + tk] = tmp[j];
      __syncthreads();
      cur ^= 1;
    }
  }
}

// ---------------- host orchestration ----------------------------------------
extern "C" void kernel_launch(void* const* d_in, const int* in_sizes, int n_in,
                              void* d_out, int out_size, void* d_ws, size_t ws_size,
                              hipStream_t stream)
{
  const float* x_in  = (const float*)d_in[0];
  const float* n1w   = (const float*)d_in[1];
  const float* n1b   = (const float*)d_in[2];
  const float* qkvw  = (const float*)d_in[3];
  const float* qkvb  = (const float*)d_in[4];
  const float* btab  = (const float*)d_in[5];
  const float* projw = (const float*)d_in[6];
  const float* projb = (const float*)d_in[7];
  const float* n2w   = (const float*)d_in[8];
  const float* n2b   = (const float*)d_in[9];
  const float* w1    = (const float*)d_in[10];
  const float* b1    = (const float*)d_in[11];
  const float* w2    = (const float*)d_in[12];
  const float* b2    = (const float*)d_in[13];

  char* ws = (char*)d_ws;
  float* x            = (float*)(ws);                          // 113,246,208 B
  __hip_bfloat16* xw  = (__hip_bfloat16*)(ws + 113246208);     //  56,623,104 B
  __hip_bfloat16* qb  = (__hip_bfloat16*)(ws + 169869312);     // q,k,v,o head-major
  __hip_bfloat16* kb  = qb + 28311552;
  __hip_bfloat16* vb  = kb + 28311552;
  __hip_bfloat16* ob  = vb + 28311552;
  __hip_bfloat16* tb  = qb;                                    // MLP intermediate reuse
  __hip_bfloat16* biasb = (__hip_bfloat16*)(ws + 396361728);   //  15,925,248 B
  __hip_bfloat16* wqkvT  = (__hip_bfloat16*)(ws + 428212224);
  __hip_bfloat16* wprojT = wqkvT + 110592;
  __hip_bfloat16* w1T    = wprojT + 36864;
  __hip_bfloat16* w2T    = w1T + 147456;

  hipMemcpyAsync(x, x_in, (size_t)L_TOK * 192 * 4, hipMemcpyDeviceToDevice, stream);

  for (int layer = 0; layer < 2; layer++) {
    int sz = layer ? 1 : 0, sh = layer ? 3 : 0, sw = layer ? 6 : 0;
    int masked = layer;

    convT_kernel<<<(110592 + 255) / 256, 256, 0, stream>>>(qkvw + (long)layer * 110592, wqkvT, 192, 576);
    convT_kernel<<<(36864 + 255) / 256, 256, 0, stream>>>(projw + (long)layer * 36864, wprojT, 192, 192);
    convT_kernel<<<(147456 + 255) / 256, 256, 0, stream>>>(w1 + (long)layer * 147456, w1T, 192, 768);
    convT_kernel<<<(147456 + 255) / 256, 256, 0, stream>>>(w2 + (long)layer * 147456, w2T, 768, 192);
    biaspre_kernel<<<dim3(384, 9), 256, 0, stream>>>(btab + (long)layer * 3312 * 384, biasb);

    ln_kernel<<<36864, 256, 0, stream>>>(x, n1w + layer * 192, n1b + layer * 192, xw, sz, sh, sw, 1);
    gemm_kernel<0, 0><<<dim3(1152, 9), 256, 0, stream>>>(
        xw, wqkvT, qkvb + layer * 576, 192, qb, kb, vb, nullptr, nullptr, 0, 0, 0, 0);
    attn_kernel<<<768, 576, 0, stream>>>(qb, kb, vb, biasb, ob, masked);
    gemm_kernel<1, 0><<<dim3(1152, 3), 256, 0, stream>>>(
        ob, wprojT, projb + layer * 192, 192, nullptr, nullptr, nullptr, x, nullptr, sz, sh, sw, 0);
    ln_kernel<<<36864, 256, 0, stream>>>(x, n2w + layer * 192, n2b + layer * 192, xw, 0, 0, 0, 0);
    gemm_kernel<2, 0><<<dim3(1152, 12), 256, 0, stream>>>(
        xw, w1T, b1 + layer * 768, 192, tb, nullptr, nullptr, nullptr, nullptr, 0, 0, 0, 768);
    if (layer == 0)
      gemm_kernel<3, 0><<<dim3(1152, 3), 256, 0, stream>>>(
          tb, w2T, b2 + layer * 192, 768, nullptr, nullptr, nullptr, x, nullptr, 0, 0, 0, 192);
    else
      gemm_kernel<3, 1><<<dim3(1152, 3), 256, 0, stream>>>(
          tb, w2T, b2 + layer * 192, 768, nullptr, nullptr, nullptr, x,
          (float*)d_out, 0, 0, 0, 192);
  }
}